// Round 10
// baseline (993.411 us; speedup 1.0000x reference)
//
#include <hip/hip_runtime.h>

#define T_STEPS 2048
#define HID 64

typedef __attribute__((ext_vector_type(8))) short short8;
typedef __attribute__((ext_vector_type(4))) float f32x4;

static __device__ __forceinline__ unsigned short f2bf(float f) {
    unsigned int uu = __float_as_uint(f);
    uu = uu + 0x7fffu + ((uu >> 16) & 1u);   // RNE; inputs finite
    return (unsigned short)(uu >> 16);
}
static __device__ __forceinline__ float exp2_f(float x) {
#if __has_builtin(__builtin_amdgcn_exp2f)
    return __builtin_amdgcn_exp2f(x);
#else
    return exp2f(x);
#endif
}
// weights pre-scaled by -log2e (sigma) / -2log2e (tanh): act = rcp(1+2^s)
static __device__ __forceinline__ float sig2(float s) {
    return __builtin_amdgcn_rcpf(1.0f + exp2_f(s));
}
static __device__ __forceinline__ float tanh2(float s) {
    return fmaf(2.0f, __builtin_amdgcn_rcpf(1.0f + exp2_f(s)), -1.0f);
}
#define NLOG2E 1.4426950408889634f

// TWO batches/block (256 blocks, 1/CU), 8 waves: waves 0-3 = layer0, 4-7 =
// layer1. R10: the per-step block-wide s_barrier (which phase-locked all 8
// waves: simultaneous ds_read, then MFMA contention, then VALU) is replaced
// by DATA-FLOW sync: depth-4 h slots (t&3) + two cumulative LDS counters.
//   L0 step t waits: cnt0>=4t (group lockstep), cnt1>=4(t-3) (slot reuse).
//   L1 step s waits: cnt0>=4(s+1) (h0(s) ready),  cnt1>=4s  (group lockstep).
// Publish: ds-release (lgkmcnt(0)) then lane0 atomicAdd. Acquire: polled
// volatile ds_read_b64 of both counters + lgkmcnt fence + sched_barrier.
// L0 free-runs up to 3 steps ahead -> wave groups de-phase, MFMA of one
// hides LDS/act latency of the other. Deterministic (counters gate only).
// Swapped MFMA, batches in M rows 0/4; lg0/lg1 lanes own batch0/1 at acc[0].
__global__ void __launch_bounds__(512, 1) __attribute__((amdgpu_waves_per_eu(2, 2)))
lstm2_df(const float* __restrict__ x,
         const float* __restrict__ wih0, const float* __restrict__ whh0,
         const float* __restrict__ bih0, const float* __restrict__ bhh0,
         const float* __restrict__ wih1, const float* __restrict__ whh1,
         const float* __restrict__ bih1, const float* __restrict__ bhh1,
         float* __restrict__ out, int B)
{
    __shared__ __align__(16) unsigned short s_h0[4][2][HID];  // depth-4 slots
    __shared__ __align__(16) unsigned short s_h1[4][2][HID];
    __shared__ __align__(8)  unsigned s_cnt[2];               // [0]=L0, [1]=L1 completions
    __shared__ __align__(16) float s_xf[2 * T_STEPS * 4];     // 64 KB x f32

    const int tid  = threadIdx.x;
    const int lane = tid & 63;
    const int wv   = tid >> 6;
    const int wg   = wv >> 2;       // 0 = L0 group, 1 = L1 group
    const int wl   = wv & 3;        // units 16wl..16wl+15
    const int l15  = lane & 15;
    const int lg   = lane >> 4;
    const int b0   = 2 * blockIdx.x;
    const int u    = 16 * wl + l15;
    const int bx   = lg & 1;
    const int rsel = (l15 >> 2) & 1;

    const float SCL[4] = {-NLOG2E, -NLOG2E, -2.0f * NLOG2E, -NLOG2E};

    // ---------------- stage x, zero h slots + counters ----------------
    const float4* __restrict__ xb4 = (const float4*)(x + (size_t)b0 * (T_STEPS * 4));
    float4* s_xf4 = (float4*)s_xf;
    for (int i2 = tid; i2 < 2 * T_STEPS; i2 += 512) s_xf4[i2] = xb4[i2];
    if (tid < 256) {
        ((unsigned short*)s_h0)[tid] = 0; ((unsigned short*)s_h0)[tid + 256] = 0;
        ((unsigned short*)s_h1)[tid] = 0; ((unsigned short*)s_h1)[tid + 256] = 0;
    }
    if (tid == 0) { s_cnt[0] = 0; s_cnt[1] = 0; }
    __syncthreads();

    const size_t BTH = (size_t)B * T_STEPS * HID;
    const size_t BH  = (size_t)B * HID;
    const size_t bi  = (size_t)(b0 + bx) * HID + u;
    const f32x4 Z = {0.f, 0.f, 0.f, 0.f};

    // acquire: wait cnt0>=T0 && cnt1>=T1 (one ds_read_b64 when satisfied)
    auto poll2 = [&](int T0, int T1) {
        if (T0 <= 0 && T1 <= 0) return;
        const unsigned uT0 = (T0 > 0) ? (unsigned)T0 : 0u;
        const unsigned uT1 = (T1 > 0) ? (unsigned)T1 : 0u;
        volatile unsigned long long* pc = (volatile unsigned long long*)&s_cnt[0];
        unsigned long long cc = *pc;
        while ((unsigned)cc < uT0 || (unsigned)(cc >> 32) < uT1) {
            __builtin_amdgcn_s_sleep(1);
            cc = *pc;
        }
        asm volatile("s_waitcnt lgkmcnt(0)" ::: "memory");
        __builtin_amdgcn_sched_barrier(0);
    };
    // release: h-write drained, then one increment per wave
    auto publish = [&](int which) {
        asm volatile("s_waitcnt lgkmcnt(0)" ::: "memory");
        if (lane == 0) atomicAdd(&s_cnt[which], 1u);
    };

    if (wg == 0) {
        // =================== layer0 wave group ===================
        short8 W0[4][2];
        float  wx[4][4];
        f32x4  Bias0[4];
        #pragma unroll
        for (int ni = 0; ni < 4; ++ni) {
            const int g = 64 * ni + u;
            const float sc = SCL[ni];
            #pragma unroll
            for (int kt = 0; kt < 2; ++kt)
                #pragma unroll
                for (int j = 0; j < 8; ++j)
                    W0[ni][kt][j] = (short)f2bf(whh0[g * HID + kt * 32 + lg * 8 + j] * sc);
            #pragma unroll
            for (int j = 0; j < 4; ++j) wx[ni][j] = wih0[g * 4 + j] * sc;
            const float bb = (bih0[g] + bhh0[g]) * sc;
            Bias0[ni] = (f32x4){bb, bb, bb, bb};
        }
        float c0s = 0.f, h0s = 0.f;
        const float* xcur = &s_xf[(size_t)bx * T_STEPS * 4];

        auto l0_step = [&](int t, int P) {
            const int Q = (P + 3) & 3;
            poll2(4 * t, 4 * (t - 3));
            const short8 Ha = *(const short8*)&s_h0[Q][rsel][8 * lg];   // h0(t-1)
            const short8 Hb = *(const short8*)&s_h0[Q][rsel][32 + 8 * lg];
            const float4 xt = *(const float4*)xcur;  xcur += 4;
            __builtin_amdgcn_s_setprio(1);
            f32x4 aA0 = __builtin_amdgcn_mfma_f32_16x16x32_bf16(Ha, W0[0][0], Bias0[0], 0, 0, 0);
            f32x4 aA1 = __builtin_amdgcn_mfma_f32_16x16x32_bf16(Ha, W0[1][0], Bias0[1], 0, 0, 0);
            f32x4 aA2 = __builtin_amdgcn_mfma_f32_16x16x32_bf16(Ha, W0[2][0], Bias0[2], 0, 0, 0);
            f32x4 aA3 = __builtin_amdgcn_mfma_f32_16x16x32_bf16(Ha, W0[3][0], Bias0[3], 0, 0, 0);
            f32x4 aB0 = __builtin_amdgcn_mfma_f32_16x16x32_bf16(Hb, W0[0][1], Z, 0, 0, 0);
            f32x4 aB1 = __builtin_amdgcn_mfma_f32_16x16x32_bf16(Hb, W0[1][1], Z, 0, 0, 0);
            f32x4 aB2 = __builtin_amdgcn_mfma_f32_16x16x32_bf16(Hb, W0[2][1], Z, 0, 0, 0);
            f32x4 aB3 = __builtin_amdgcn_mfma_f32_16x16x32_bf16(Hb, W0[3][1], Z, 0, 0, 0);
            __builtin_amdgcn_s_setprio(0);
            float s0 = aA0[0] + aB0[0];
            float s1 = aA1[0] + aB1[0];
            float s2 = aA2[0] + aB2[0];
            float s3 = aA3[0] + aB3[0];
            s0 = fmaf(wx[0][0], xt.x, s0); s0 = fmaf(wx[0][1], xt.y, s0);
            s0 = fmaf(wx[0][2], xt.z, s0); s0 = fmaf(wx[0][3], xt.w, s0);
            s1 = fmaf(wx[1][0], xt.x, s1); s1 = fmaf(wx[1][1], xt.y, s1);
            s1 = fmaf(wx[1][2], xt.z, s1); s1 = fmaf(wx[1][3], xt.w, s1);
            s2 = fmaf(wx[2][0], xt.x, s2); s2 = fmaf(wx[2][1], xt.y, s2);
            s2 = fmaf(wx[2][2], xt.z, s2); s2 = fmaf(wx[2][3], xt.w, s2);
            s3 = fmaf(wx[3][0], xt.x, s3); s3 = fmaf(wx[3][1], xt.y, s3);
            s3 = fmaf(wx[3][2], xt.z, s3); s3 = fmaf(wx[3][3], xt.w, s3);
            float i_ = sig2(s0);
            float f_ = sig2(s1);
            float g_ = tanh2(s2);
            float o_ = sig2(s3);
            c0s = fmaf(f_, c0s, i_ * g_);
            h0s = o_ * tanh2(c0s * (-2.0f * NLOG2E));
            if (lg < 2) s_h0[P][lg][u] = f2bf(h0s);
            publish(0);
        };

        for (int it = 0; it < T_STEPS / 4; ++it) {
            const int tb = 4 * it;
            l0_step(tb + 0, 0);
            l0_step(tb + 1, 1);
            l0_step(tb + 2, 2);
            l0_step(tb + 3, 3);
        }
        if (lg < 2) {
            out[BTH + bi]          = h0s;   // h_n layer0
            out[BTH + 2 * BH + bi] = c0s;   // c_n layer0
        }
    } else {
        // =================== layer1 wave group ===================
        short8 W1[4][4];
        f32x4  Bias1[4];
        #pragma unroll
        for (int ni = 0; ni < 4; ++ni) {
            const int g = 64 * ni + u;
            const float sc = SCL[ni];
            #pragma unroll
            for (int kt = 0; kt < 2; ++kt)
                #pragma unroll
                for (int j = 0; j < 8; ++j) {
                    W1[ni][kt][j]     = (short)f2bf(wih1[g * HID + kt * 32 + lg * 8 + j] * sc);
                    W1[ni][2 + kt][j] = (short)f2bf(whh1[g * HID + kt * 32 + lg * 8 + j] * sc);
                }
            const float bb = (bih1[g] + bhh1[g]) * sc;
            Bias1[ni] = (f32x4){bb, bb, bb, bb};
        }
        float c1s = 0.f, h1s = 0.f;
        float* __restrict__ opp = out + (size_t)(b0 + bx) * T_STEPS * HID + u;

        auto l1_step = [&](int s, int P) {   // P = s&3
            const int Q = (P + 3) & 3;
            poll2(4 * (s + 1), 4 * s);
            const short8 Ha = *(const short8*)&s_h0[P][rsel][8 * lg];   // h0(s)
            const short8 Hb = *(const short8*)&s_h0[P][rsel][32 + 8 * lg];
            const short8 Ga = *(const short8*)&s_h1[Q][rsel][8 * lg];   // h1(s-1)
            const short8 Gb = *(const short8*)&s_h1[Q][rsel][32 + 8 * lg];
            __builtin_amdgcn_s_setprio(1);
            f32x4 dH0 = __builtin_amdgcn_mfma_f32_16x16x32_bf16(Ha, W1[0][0], Bias1[0], 0, 0, 0);
            f32x4 dH1 = __builtin_amdgcn_mfma_f32_16x16x32_bf16(Ha, W1[1][0], Bias1[1], 0, 0, 0);
            f32x4 dH2 = __builtin_amdgcn_mfma_f32_16x16x32_bf16(Ha, W1[2][0], Bias1[2], 0, 0, 0);
            f32x4 dH3 = __builtin_amdgcn_mfma_f32_16x16x32_bf16(Ha, W1[3][0], Bias1[3], 0, 0, 0);
            f32x4 dG0 = __builtin_amdgcn_mfma_f32_16x16x32_bf16(Ga, W1[0][2], Z, 0, 0, 0);
            f32x4 dG1 = __builtin_amdgcn_mfma_f32_16x16x32_bf16(Ga, W1[1][2], Z, 0, 0, 0);
            f32x4 dG2 = __builtin_amdgcn_mfma_f32_16x16x32_bf16(Ga, W1[2][2], Z, 0, 0, 0);
            f32x4 dG3 = __builtin_amdgcn_mfma_f32_16x16x32_bf16(Ga, W1[3][2], Z, 0, 0, 0);
            dH0 = __builtin_amdgcn_mfma_f32_16x16x32_bf16(Hb, W1[0][1], dH0, 0, 0, 0);
            dH1 = __builtin_amdgcn_mfma_f32_16x16x32_bf16(Hb, W1[1][1], dH1, 0, 0, 0);
            dH2 = __builtin_amdgcn_mfma_f32_16x16x32_bf16(Hb, W1[2][1], dH2, 0, 0, 0);
            dH3 = __builtin_amdgcn_mfma_f32_16x16x32_bf16(Hb, W1[3][1], dH3, 0, 0, 0);
            dG0 = __builtin_amdgcn_mfma_f32_16x16x32_bf16(Gb, W1[0][3], dG0, 0, 0, 0);
            dG1 = __builtin_amdgcn_mfma_f32_16x16x32_bf16(Gb, W1[1][3], dG1, 0, 0, 0);
            dG2 = __builtin_amdgcn_mfma_f32_16x16x32_bf16(Gb, W1[2][3], dG2, 0, 0, 0);
            dG3 = __builtin_amdgcn_mfma_f32_16x16x32_bf16(Gb, W1[3][3], dG3, 0, 0, 0);
            __builtin_amdgcn_s_setprio(0);
            float i_ = sig2(dH0[0] + dG0[0]);
            float f_ = sig2(dH1[0] + dG1[0]);
            float g_ = tanh2(dH2[0] + dG2[0]);
            float o_ = sig2(dH3[0] + dG3[0]);
            c1s = fmaf(f_, c1s, i_ * g_);
            h1s = o_ * tanh2(c1s * (-2.0f * NLOG2E));
            if (lg < 2) {
                s_h1[P][lg][u] = f2bf(h1s);
                *opp = h1s;                  // out1[b,s]; stays in flight
            }
            opp += HID;
            publish(1);
        };

        for (int it = 0; it < T_STEPS / 4; ++it) {
            const int sb = 4 * it;
            l1_step(sb + 0, 0);
            l1_step(sb + 1, 1);
            l1_step(sb + 2, 2);
            l1_step(sb + 3, 3);
        }
        if (lg < 2) {
            out[BTH + BH + bi]     = h1s;   // h_n layer1
            out[BTH + 3 * BH + bi] = c1s;   // c_n layer1
        }
    }
}

extern "C" void kernel_launch(void* const* d_in, const int* in_sizes, int n_in,
                              void* d_out, int out_size, void* d_ws, size_t ws_size,
                              hipStream_t stream) {
    const float* x    = (const float*)d_in[0];
    const float* wih0 = (const float*)d_in[1];
    const float* whh0 = (const float*)d_in[2];
    const float* bih0 = (const float*)d_in[3];
    const float* bhh0 = (const float*)d_in[4];
    const float* wih1 = (const float*)d_in[5];
    const float* whh1 = (const float*)d_in[6];
    const float* bih1 = (const float*)d_in[7];
    const float* bhh1 = (const float*)d_in[8];
    float* out = (float*)d_out;

    const int B = in_sizes[0] / (T_STEPS * 4);   // 512

    lstm2_df<<<dim3(B / 2), dim3(512), 0, stream>>>(
        x, wih0, whh0, bih0, bhh0, wih1, whh1, bih1, bhh1, out, B);
}

// Round 11
// 865.649 us; speedup vs baseline: 1.1476x; 1.1476x over previous
//
#include <hip/hip_runtime.h>

#define T_STEPS 2048
#define HID 64

typedef __attribute__((ext_vector_type(8))) short short8;
typedef __attribute__((ext_vector_type(4))) float f32x4;

static __device__ __forceinline__ unsigned short f2bf(float f) {
    unsigned int uu = __float_as_uint(f);
    uu = uu + 0x7fffu + ((uu >> 16) & 1u);   // RNE; inputs finite
    return (unsigned short)(uu >> 16);
}
static __device__ __forceinline__ float exp2_f(float x) {
#if __has_builtin(__builtin_amdgcn_exp2f)
    return __builtin_amdgcn_exp2f(x);
#else
    return exp2f(x);
#endif
}
#define NLOG2E 1.4426950408889634f

// TWO batches/block (256 blocks, 1/CU), 8 waves: 0-3 = L0, 4-7 = L1.
// R11: ANTI-PHASED two-window schedule. R9's single barrier aligned all waves
// into the same phase (MFMA 466cy THEN acts ~500cy, summed). Now each step has
// two windows; in each window one group issues MFMA while the other runs acts:
//   A: L0 {ds_read h0(t-1), 8 MFMA}   | L1 {acts(t-2)+h1/out1 write, 8 ih-MFMA(t-1)}
//   B: L0 {acts(t)+h0 write}          | L1 {ds_read h1(t-2), 8 hh-MFMA(t-1)}
// Trans-split acts: rows 8/12 carry valid b0/b1 DUPLICATES (rsel mirrors), so
// lg0/1 compute {i,g}, lg2/3 {f,o} (branchless affine on rcp(1+2^s)); one
// shfl_xor(32) pair merges -> 6 trans/cell (was 10). c-chain duplicated, only
// lg<2 writes. exp2-folded weights as R9. Raw barriers (lgkmcnt-only wait).
__global__ void __launch_bounds__(512, 1) __attribute__((amdgpu_waves_per_eu(2, 2)))
lstm2_ap(const float* __restrict__ x,
         const float* __restrict__ wih0, const float* __restrict__ whh0,
         const float* __restrict__ bih0, const float* __restrict__ bhh0,
         const float* __restrict__ wih1, const float* __restrict__ whh1,
         const float* __restrict__ bih1, const float* __restrict__ bhh1,
         float* __restrict__ out, int B)
{
    __shared__ __align__(16) unsigned short s_h0[2][2][HID];  // [pingpong][batch][unit]
    __shared__ __align__(16) unsigned short s_h1[2][2][HID];
    __shared__ __align__(16) float s_xf[2 * T_STEPS * 4];     // 64 KB x f32

    const int tid  = threadIdx.x;
    const int lane = tid & 63;
    const int wv   = tid >> 6;
    const int wg   = wv >> 2;        // 0 = L0 group, 1 = L1 group
    const int wl   = wv & 3;         // units 16wl..16wl+15
    const int l15  = lane & 15;
    const int lg   = lane >> 4;
    const int b0   = 2 * blockIdx.x;
    const int u    = 16 * wl + l15;
    const int bx   = lg & 1;         // batch for acts/out (all lg valid now)
    const int rsel = (l15 >> 2) & 1; // A-row h: rows 0,8->b0; 4,12->b1
    const int half = lg >> 1;        // 0: this lane does {i,g}; 1: {f,o}

    const float SCL[4] = {-NLOG2E, -NLOG2E, -2.0f * NLOG2E, -NLOG2E};
    const int   tA = half ? 1 : 0;   // sigmoid gate (i or f)
    const int   tB = half ? 3 : 2;   // second gate (g=tanh or o=sigmoid)
    const float aselB = half ? 1.0f : 2.0f;   // vB = aselB*rcp(1+2^s)+cselB
    const float cselB = half ? 0.0f : -1.0f;

    // ---------------- stage x, zero h, sync ----------------
    const float4* __restrict__ xb4 = (const float4*)(x + (size_t)b0 * (T_STEPS * 4));
    float4* s_xf4 = (float4*)s_xf;
    for (int i2 = tid; i2 < 2 * T_STEPS; i2 += 512) s_xf4[i2] = xb4[i2];
    if (tid < 256) {
        ((unsigned short*)s_h0)[tid] = 0;
        ((unsigned short*)s_h1)[tid] = 0;
    }

    const size_t BTH = (size_t)B * T_STEPS * HID;
    const size_t BH  = (size_t)B * HID;
    const size_t bi  = (size_t)(b0 + bx) * HID + u;
    const f32x4 Z = {0.f, 0.f, 0.f, 0.f};

    #define BAR() do { asm volatile("s_waitcnt lgkmcnt(0)" ::: "memory"); \
                       __builtin_amdgcn_s_barrier(); } while (0)

    if (wg == 0) {
        // =================== layer0 wave group ===================
        short8 W0[4][2];     // Whh0^T frags (pre-scaled per type)
        f32x4  Bias0[4];
        float  wxA[4], wxB[4];   // this lane's 2 Wih0 rows (pre-scaled)
        #pragma unroll
        for (int ni = 0; ni < 4; ++ni) {
            const int g = 64 * ni + u;
            const float sc = SCL[ni];
            #pragma unroll
            for (int kt = 0; kt < 2; ++kt)
                #pragma unroll
                for (int j = 0; j < 8; ++j)
                    W0[ni][kt][j] = (short)f2bf(whh0[g * HID + kt * 32 + lg * 8 + j] * sc);
            const float bb = (bih0[g] + bhh0[g]) * sc;
            Bias0[ni] = (f32x4){bb, bb, bb, bb};
        }
        {
            const int gA = 64 * tA + u, gB = 64 * tB + u;
            #pragma unroll
            for (int j = 0; j < 4; ++j) {
                wxA[j] = wih0[gA * 4 + j] * SCL[tA];
                wxB[j] = wih0[gB * 4 + j] * SCL[tB];
            }
        }
        float c0s = 0.f, h0s = 0.f;
        float sA0 = 0.f, sB0 = 0.f;
        float4 xt = {0.f, 0.f, 0.f, 0.f};
        const float* xcur = &s_xf[(size_t)bx * T_STEPS * 4];
        __syncthreads();

        // window A: ds_read + 8 MFMA for h0(t); carry 2 scalars
        auto l0_A = [&](int P) {
            const int Q = P ^ 1;
            const short8 Ha = *(const short8*)&s_h0[Q][rsel][8 * lg];
            const short8 Hb = *(const short8*)&s_h0[Q][rsel][32 + 8 * lg];
            xt = *(const float4*)xcur;  xcur += 4;
            __builtin_amdgcn_s_setprio(1);
            f32x4 a0 = __builtin_amdgcn_mfma_f32_16x16x32_bf16(Ha, W0[0][0], Bias0[0], 0, 0, 0);
            f32x4 a1 = __builtin_amdgcn_mfma_f32_16x16x32_bf16(Ha, W0[1][0], Bias0[1], 0, 0, 0);
            f32x4 a2 = __builtin_amdgcn_mfma_f32_16x16x32_bf16(Ha, W0[2][0], Bias0[2], 0, 0, 0);
            f32x4 a3 = __builtin_amdgcn_mfma_f32_16x16x32_bf16(Ha, W0[3][0], Bias0[3], 0, 0, 0);
            a0 = __builtin_amdgcn_mfma_f32_16x16x32_bf16(Hb, W0[0][1], a0, 0, 0, 0);
            a1 = __builtin_amdgcn_mfma_f32_16x16x32_bf16(Hb, W0[1][1], a1, 0, 0, 0);
            a2 = __builtin_amdgcn_mfma_f32_16x16x32_bf16(Hb, W0[2][1], a2, 0, 0, 0);
            a3 = __builtin_amdgcn_mfma_f32_16x16x32_bf16(Hb, W0[3][1], a3, 0, 0, 0);
            __builtin_amdgcn_s_setprio(0);
            sA0 = half ? a1[0] : a0[0];
            sB0 = half ? a3[0] : a2[0];
        };
        // window B: x-FMA + split acts + h0 write
        auto l0_B = [&](int P) {
            float sa = sA0, sb = sB0;
            sa = fmaf(wxA[0], xt.x, sa); sa = fmaf(wxA[1], xt.y, sa);
            sa = fmaf(wxA[2], xt.z, sa); sa = fmaf(wxA[3], xt.w, sa);
            sb = fmaf(wxB[0], xt.x, sb); sb = fmaf(wxB[1], xt.y, sb);
            sb = fmaf(wxB[2], xt.z, sb); sb = fmaf(wxB[3], xt.w, sb);
            float vA = __builtin_amdgcn_rcpf(1.0f + exp2_f(sa));            // i or f
            float vB = fmaf(aselB, __builtin_amdgcn_rcpf(1.0f + exp2_f(sb)), cselB); // g or o
            float oA = __shfl_xor(vA, 32);
            float oB = __shfl_xor(vB, 32);
            float i_ = half ? oA : vA;
            float f_ = half ? vA : oA;
            float g_ = half ? oB : vB;
            float o_ = half ? vB : oB;
            c0s = fmaf(f_, c0s, i_ * g_);
            float tc = fmaf(2.0f, __builtin_amdgcn_rcpf(1.0f + exp2_f(c0s * (-2.0f * NLOG2E))), -1.0f);
            h0s = o_ * tc;
            if (lg < 2) s_h0[P][lg][u] = f2bf(h0s);
        };

        // t=0,1 prologue
        l0_A(0); BAR(); l0_B(0); BAR();
        l0_A(1); BAR(); l0_B(1); BAR();
        // main t=2..T-1
        for (int it = 0; it < (T_STEPS - 2) / 2; ++it) {
            l0_A(0); BAR(); l0_B(0); BAR();
            l0_A(1); BAR(); l0_B(1); BAR();
        }
        // t=T epilogue (no L0 work, match barriers)
        BAR(); BAR();
        if (lg < 2) {
            out[BTH + bi]          = h0s;   // h_n layer0
            out[BTH + 2 * BH + bi] = c0s;   // c_n layer0
        }
    } else {
        // =================== layer1 wave group ===================
        short8 W1[4][4];   // kt0/1 = Wih1^T (k=h0), kt2/3 = Whh1^T (k=h1)
        f32x4  Bias1[4];
        #pragma unroll
        for (int ni = 0; ni < 4; ++ni) {
            const int g = 64 * ni + u;
            const float sc = SCL[ni];
            #pragma unroll
            for (int kt = 0; kt < 2; ++kt)
                #pragma unroll
                for (int j = 0; j < 8; ++j) {
                    W1[ni][kt][j]     = (short)f2bf(wih1[g * HID + kt * 32 + lg * 8 + j] * sc);
                    W1[ni][2 + kt][j] = (short)f2bf(whh1[g * HID + kt * 32 + lg * 8 + j] * sc);
                }
            const float bb = (bih1[g] + bhh1[g]) * sc;
            Bias1[ni] = (f32x4){bb, bb, bb, bb};
        }
        float c1s = 0.f, h1s = 0.f;
        float sA1 = 0.f, sB1 = 0.f;
        f32x4 d0 = Z, d1 = Z, d2 = Z, d3 = Z;
        float* __restrict__ opp = out + (size_t)(b0 + bx) * T_STEPS * HID + u;
        __syncthreads();

        // window A part 1: acts for step t-2 (consumes sA1/sB1 from prev B)
        auto l1_actsA = [&](int Pwr) {
            float vA = __builtin_amdgcn_rcpf(1.0f + exp2_f(sA1));
            float vB = fmaf(aselB, __builtin_amdgcn_rcpf(1.0f + exp2_f(sB1)), cselB);
            float oA = __shfl_xor(vA, 32);
            float oB = __shfl_xor(vB, 32);
            float i_ = half ? oA : vA;
            float f_ = half ? vA : oA;
            float g_ = half ? oB : vB;
            float o_ = half ? vB : oB;
            c1s = fmaf(f_, c1s, i_ * g_);
            float tc = fmaf(2.0f, __builtin_amdgcn_rcpf(1.0f + exp2_f(c1s * (-2.0f * NLOG2E))), -1.0f);
            h1s = o_ * tc;
            if (lg < 2) {
                s_h1[Pwr][lg][u] = f2bf(h1s);
                *opp = h1s;                  // out1; stays in flight across BAR
            }
            opp += HID;
        };
        // window A part 2: ih-MFMA for step t-1 (reads h0(t-1))
        auto l1_ihA = [&](int Ph0) {
            const short8 Ha = *(const short8*)&s_h0[Ph0][rsel][8 * lg];
            const short8 Hb = *(const short8*)&s_h0[Ph0][rsel][32 + 8 * lg];
            __builtin_amdgcn_s_setprio(1);
            d0 = __builtin_amdgcn_mfma_f32_16x16x32_bf16(Ha, W1[0][0], Bias1[0], 0, 0, 0);
            d1 = __builtin_amdgcn_mfma_f32_16x16x32_bf16(Ha, W1[1][0], Bias1[1], 0, 0, 0);
            d2 = __builtin_amdgcn_mfma_f32_16x16x32_bf16(Ha, W1[2][0], Bias1[2], 0, 0, 0);
            d3 = __builtin_amdgcn_mfma_f32_16x16x32_bf16(Ha, W1[3][0], Bias1[3], 0, 0, 0);
            d0 = __builtin_amdgcn_mfma_f32_16x16x32_bf16(Hb, W1[0][1], d0, 0, 0, 0);
            d1 = __builtin_amdgcn_mfma_f32_16x16x32_bf16(Hb, W1[1][1], d1, 0, 0, 0);
            d2 = __builtin_amdgcn_mfma_f32_16x16x32_bf16(Hb, W1[2][1], d2, 0, 0, 0);
            d3 = __builtin_amdgcn_mfma_f32_16x16x32_bf16(Hb, W1[3][1], d3, 0, 0, 0);
            __builtin_amdgcn_s_setprio(0);
        };
        // window B: hh-MFMA accumulate (reads h1(t-2)), then select scalars
        auto l1_hhB = [&](int Ph1) {
            const short8 Ga = *(const short8*)&s_h1[Ph1][rsel][8 * lg];
            const short8 Gb = *(const short8*)&s_h1[Ph1][rsel][32 + 8 * lg];
            __builtin_amdgcn_s_setprio(1);
            d0 = __builtin_amdgcn_mfma_f32_16x16x32_bf16(Ga, W1[0][2], d0, 0, 0, 0);
            d1 = __builtin_amdgcn_mfma_f32_16x16x32_bf16(Ga, W1[1][2], d1, 0, 0, 0);
            d2 = __builtin_amdgcn_mfma_f32_16x16x32_bf16(Ga, W1[2][2], d2, 0, 0, 0);
            d3 = __builtin_amdgcn_mfma_f32_16x16x32_bf16(Ga, W1[3][2], d3, 0, 0, 0);
            d0 = __builtin_amdgcn_mfma_f32_16x16x32_bf16(Gb, W1[0][3], d0, 0, 0, 0);
            d1 = __builtin_amdgcn_mfma_f32_16x16x32_bf16(Gb, W1[1][3], d1, 0, 0, 0);
            d2 = __builtin_amdgcn_mfma_f32_16x16x32_bf16(Gb, W1[2][3], d2, 0, 0, 0);
            d3 = __builtin_amdgcn_mfma_f32_16x16x32_bf16(Gb, W1[3][3], d3, 0, 0, 0);
            __builtin_amdgcn_s_setprio(0);
            sA1 = half ? d1[0] : d0[0];
            sB1 = half ? d3[0] : d2[0];
        };

        // t=0: no L1 work
        BAR(); BAR();
        // t=1: ih(0) in A; hh(0) in B
        l1_ihA(0); BAR(); l1_hhB(1); BAR();
        // main t=2..T-1
        for (int it = 0; it < (T_STEPS - 2) / 2; ++it) {
            l1_actsA(0); l1_ihA(1); BAR(); l1_hhB(0); BAR();   // t even
            l1_actsA(1); l1_ihA(0); BAR(); l1_hhB(1); BAR();   // t odd
        }
        // t=T (=2048, even): acts(T-2), ih(T-1), hh(T-1)
        l1_actsA(0); l1_ihA(1); BAR(); l1_hhB(0); BAR();
        // t=T+1: acts(T-1), no barrier
        l1_actsA(1);
        if (lg < 2) {
            out[BTH + BH + bi]     = h1s;   // h_n layer1
            out[BTH + 3 * BH + bi] = c1s;   // c_n layer1
        }
    }
    #undef BAR
}

extern "C" void kernel_launch(void* const* d_in, const int* in_sizes, int n_in,
                              void* d_out, int out_size, void* d_ws, size_t ws_size,
                              hipStream_t stream) {
    const float* x    = (const float*)d_in[0];
    const float* wih0 = (const float*)d_in[1];
    const float* whh0 = (const float*)d_in[2];
    const float* bih0 = (const float*)d_in[3];
    const float* bhh0 = (const float*)d_in[4];
    const float* wih1 = (const float*)d_in[5];
    const float* whh1 = (const float*)d_in[6];
    const float* bih1 = (const float*)d_in[7];
    const float* bhh1 = (const float*)d_in[8];
    float* out = (float*)d_out;

    const int B = in_sizes[0] / (T_STEPS * 4);   // 512

    lstm2_ap<<<dim3(B / 2), dim3(512), 0, stream>>>(
        x, wih0, whh0, bih0, bhh0, wih1, whh1, bih1, bhh1, out, B);
}

// Round 12
// 787.548 us; speedup vs baseline: 1.2614x; 1.0992x over previous
//
#include <hip/hip_runtime.h>

#define T_STEPS 2048
#define HID 64

typedef __attribute__((ext_vector_type(8))) short short8;
typedef __attribute__((ext_vector_type(4))) float f32x4;

static __device__ __forceinline__ unsigned short f2bf(float f) {
    unsigned int uu = __float_as_uint(f);
    uu = uu + 0x7fffu + ((uu >> 16) & 1u);   // RNE; inputs finite
    return (unsigned short)(uu >> 16);
}
static __device__ __forceinline__ float exp2_f(float x) {
#if __has_builtin(__builtin_amdgcn_exp2f)
    return __builtin_amdgcn_exp2f(x);
#else
    return exp2f(x);
#endif
}
#define NLOG2E 1.4426950408889634f

// R12 = R9 schedule (single raw barrier/step, wave-specialized L0/L1, 2x
// unrolled static ping-pong, exp2-folded weights, split MFMA chains, setprio)
// + R11's trans-split activations (validated there, schedule reverted):
//   lane (lg,l15) computes only 2 gates -- half=lg>>1: 0 -> {i, g(tanh)},
//   1 -> {f, o} -- via branchless affine on rcp(1+2^s); one shfl_xor(32)
//   pair merges all 4 gates into every lane (DS pipe, not VALU). c-chain on
//   all lanes (duplicated), only lg<2 writes h/out1/final states.
// L0 x-path: 8 FMAs (2 Wih0 rows per lane, pre-scaled).
// MFMA C-rows 8/12 are batch0/1 duplicates (A rows 8/12 loaded with rsel
// mirrors) so lg2/3 acc[0] is valid -- what makes the split possible.
// TWO batches/block, 256 blocks, 1 block/CU, 8 waves (4 L0 + 4 L1).
__global__ void __launch_bounds__(512, 1) __attribute__((amdgpu_waves_per_eu(2, 2)))
lstm2_ts(const float* __restrict__ x,
         const float* __restrict__ wih0, const float* __restrict__ whh0,
         const float* __restrict__ bih0, const float* __restrict__ bhh0,
         const float* __restrict__ wih1, const float* __restrict__ whh1,
         const float* __restrict__ bih1, const float* __restrict__ bhh1,
         float* __restrict__ out, int B)
{
    // h arrays first: low LDS offsets -> ds_read offset: immediates
    __shared__ __align__(16) unsigned short s_h0[2][2][HID];  // [pingpong][batch][unit]
    __shared__ __align__(16) unsigned short s_h1[2][2][HID];
    __shared__ __align__(16) float s_xf[2 * T_STEPS * 4];     // 64 KB x f32

    const int tid  = threadIdx.x;
    const int lane = tid & 63;
    const int wv   = tid >> 6;       // wave 0..7
    const int wg   = wv >> 2;        // 0 = L0 group, 1 = L1 group
    const int wl   = wv & 3;         // units 16wl..16wl+15
    const int l15  = lane & 15;
    const int lg   = lane >> 4;
    const int b0   = 2 * blockIdx.x;
    const int u    = 16 * wl + l15;
    const int bx   = lg & 1;         // batch of this lane's act values
    const int rsel = (l15 >> 2) & 1; // A rows 0,8 -> b0; 4,12 -> b1
    const int half = lg >> 1;        // 0: {i,g}; 1: {f,o}

    const float SCL[4] = {-NLOG2E, -NLOG2E, -2.0f * NLOG2E, -NLOG2E};
    const int   tA = half ? 1 : 0;            // sigmoid gate (i or f)
    const int   tB = half ? 3 : 2;            // g (tanh) or o (sigmoid)
    const float aselB = half ? 1.0f : 2.0f;   // vB = aselB*rcp(1+2^s)+cselB
    const float cselB = half ? 0.0f : -1.0f;

    // ---------------- stage x, zero h ----------------
    const float4* __restrict__ xb4 = (const float4*)(x + (size_t)b0 * (T_STEPS * 4));
    float4* s_xf4 = (float4*)s_xf;
    for (int i2 = tid; i2 < 2 * T_STEPS; i2 += 512) s_xf4[i2] = xb4[i2];
    if (tid < 256) {
        ((unsigned short*)s_h0)[tid] = 0;
        ((unsigned short*)s_h1)[tid] = 0;
    }

    const size_t BTH = (size_t)B * T_STEPS * HID;
    const size_t BH  = (size_t)B * HID;
    const size_t bi  = (size_t)(b0 + bx) * HID + u;
    const f32x4 Z = {0.f, 0.f, 0.f, 0.f};

    #define BAR() do { asm volatile("s_waitcnt lgkmcnt(0)" ::: "memory"); \
                       __builtin_amdgcn_s_barrier(); } while (0)

    if (wg == 0) {
        // =================== layer0 wave group ===================
        short8 W0[4][2];     // Whh0^T frags (pre-scaled per gate type)
        f32x4  Bias0[4];
        float  wxA[4], wxB[4];   // this lane's two Wih0 rows (pre-scaled)
        #pragma unroll
        for (int ni = 0; ni < 4; ++ni) {
            const int g = 64 * ni + u;
            const float sc = SCL[ni];
            #pragma unroll
            for (int kt = 0; kt < 2; ++kt)
                #pragma unroll
                for (int j = 0; j < 8; ++j)
                    W0[ni][kt][j] = (short)f2bf(whh0[g * HID + kt * 32 + lg * 8 + j] * sc);
            const float bb = (bih0[g] + bhh0[g]) * sc;
            Bias0[ni] = (f32x4){bb, bb, bb, bb};
        }
        {
            const int gA = 64 * tA + u, gB = 64 * tB + u;
            #pragma unroll
            for (int j = 0; j < 4; ++j) {
                wxA[j] = wih0[gA * 4 + j] * SCL[tA];
                wxB[j] = wih0[gB * 4 + j] * SCL[tB];
            }
        }
        float c0s = 0.f, h0s = 0.f;
        const float* xcur = &s_xf[(size_t)bx * T_STEPS * 4];
        __syncthreads();   // staging visible

        auto l0_body = [&](int P) {
            const int Q = P ^ 1;
            const short8 Ha = *(const short8*)&s_h0[Q][rsel][8 * lg];   // h0(t-1)
            const short8 Hb = *(const short8*)&s_h0[Q][rsel][32 + 8 * lg];
            const float4 xt = *(const float4*)xcur;  xcur += 4;
            __builtin_amdgcn_s_setprio(1);
            f32x4 aA0 = __builtin_amdgcn_mfma_f32_16x16x32_bf16(Ha, W0[0][0], Bias0[0], 0, 0, 0);
            f32x4 aA1 = __builtin_amdgcn_mfma_f32_16x16x32_bf16(Ha, W0[1][0], Bias0[1], 0, 0, 0);
            f32x4 aA2 = __builtin_amdgcn_mfma_f32_16x16x32_bf16(Ha, W0[2][0], Bias0[2], 0, 0, 0);
            f32x4 aA3 = __builtin_amdgcn_mfma_f32_16x16x32_bf16(Ha, W0[3][0], Bias0[3], 0, 0, 0);
            f32x4 aB0 = __builtin_amdgcn_mfma_f32_16x16x32_bf16(Hb, W0[0][1], Z, 0, 0, 0);
            f32x4 aB1 = __builtin_amdgcn_mfma_f32_16x16x32_bf16(Hb, W0[1][1], Z, 0, 0, 0);
            f32x4 aB2 = __builtin_amdgcn_mfma_f32_16x16x32_bf16(Hb, W0[2][1], Z, 0, 0, 0);
            f32x4 aB3 = __builtin_amdgcn_mfma_f32_16x16x32_bf16(Hb, W0[3][1], Z, 0, 0, 0);
            __builtin_amdgcn_s_setprio(0);
            // my two gates' pre-activations
            float sa = half ? (aA1[0] + aB1[0]) : (aA0[0] + aB0[0]);
            float sb = half ? (aA3[0] + aB3[0]) : (aA2[0] + aB2[0]);
            sa = fmaf(wxA[0], xt.x, sa); sa = fmaf(wxA[1], xt.y, sa);
            sa = fmaf(wxA[2], xt.z, sa); sa = fmaf(wxA[3], xt.w, sa);
            sb = fmaf(wxB[0], xt.x, sb); sb = fmaf(wxB[1], xt.y, sb);
            sb = fmaf(wxB[2], xt.z, sb); sb = fmaf(wxB[3], xt.w, sb);
            float vA = __builtin_amdgcn_rcpf(1.0f + exp2_f(sa));                      // i or f
            float vB = fmaf(aselB, __builtin_amdgcn_rcpf(1.0f + exp2_f(sb)), cselB);  // g or o
            float oA = __shfl_xor(vA, 32);
            float oB = __shfl_xor(vB, 32);
            float i_ = half ? oA : vA;
            float f_ = half ? vA : oA;
            float g_ = half ? oB : vB;
            float o_ = half ? vB : oB;
            c0s = fmaf(f_, c0s, i_ * g_);
            float tc = fmaf(2.0f, __builtin_amdgcn_rcpf(1.0f + exp2_f(c0s * (-2.0f * NLOG2E))), -1.0f);
            h0s = o_ * tc;
            if (lg < 2) s_h0[P][lg][u] = f2bf(h0s);
        };

        for (int it = 0; it < T_STEPS / 2; ++it) {
            l0_body(0); BAR();
            l0_body(1); BAR();
        }
        if (lg < 2) {
            out[BTH + bi]          = h0s;   // h_n layer0
            out[BTH + 2 * BH + bi] = c0s;   // c_n layer0
        }
    } else {
        // =================== layer1 wave group ===================
        short8 W1[4][4];   // kt0/1 = Wih1^T (k=h0), kt2/3 = Whh1^T (k=h1)
        f32x4  Bias1[4];
        #pragma unroll
        for (int ni = 0; ni < 4; ++ni) {
            const int g = 64 * ni + u;
            const float sc = SCL[ni];
            #pragma unroll
            for (int kt = 0; kt < 2; ++kt)
                #pragma unroll
                for (int j = 0; j < 8; ++j) {
                    W1[ni][kt][j]     = (short)f2bf(wih1[g * HID + kt * 32 + lg * 8 + j] * sc);
                    W1[ni][2 + kt][j] = (short)f2bf(whh1[g * HID + kt * 32 + lg * 8 + j] * sc);
                }
            const float bb = (bih1[g] + bhh1[g]) * sc;
            Bias1[ni] = (f32x4){bb, bb, bb, bb};
        }
        float c1s = 0.f, h1s = 0.f;
        float* __restrict__ opp = out + (size_t)(b0 + bx) * T_STEPS * HID + u;
        __syncthreads();   // staging visible
        BAR();             // matches L0's first barrier (L1 idle at slot 0)

        auto l1_body = [&](int P) {
            const int Q = P ^ 1;
            const short8 Ha = *(const short8*)&s_h0[Q][rsel][8 * lg];   // h0(t)
            const short8 Hb = *(const short8*)&s_h0[Q][rsel][32 + 8 * lg];
            const short8 Ga = *(const short8*)&s_h1[Q][rsel][8 * lg];   // h1(t-1)
            const short8 Gb = *(const short8*)&s_h1[Q][rsel][32 + 8 * lg];
            __builtin_amdgcn_s_setprio(1);
            f32x4 dH0 = __builtin_amdgcn_mfma_f32_16x16x32_bf16(Ha, W1[0][0], Bias1[0], 0, 0, 0);
            f32x4 dH1 = __builtin_amdgcn_mfma_f32_16x16x32_bf16(Ha, W1[1][0], Bias1[1], 0, 0, 0);
            f32x4 dH2 = __builtin_amdgcn_mfma_f32_16x16x32_bf16(Ha, W1[2][0], Bias1[2], 0, 0, 0);
            f32x4 dH3 = __builtin_amdgcn_mfma_f32_16x16x32_bf16(Ha, W1[3][0], Bias1[3], 0, 0, 0);
            f32x4 dG0 = __builtin_amdgcn_mfma_f32_16x16x32_bf16(Ga, W1[0][2], Z, 0, 0, 0);
            f32x4 dG1 = __builtin_amdgcn_mfma_f32_16x16x32_bf16(Ga, W1[1][2], Z, 0, 0, 0);
            f32x4 dG2 = __builtin_amdgcn_mfma_f32_16x16x32_bf16(Ga, W1[2][2], Z, 0, 0, 0);
            f32x4 dG3 = __builtin_amdgcn_mfma_f32_16x16x32_bf16(Ga, W1[3][2], Z, 0, 0, 0);
            dH0 = __builtin_amdgcn_mfma_f32_16x16x32_bf16(Hb, W1[0][1], dH0, 0, 0, 0);
            dH1 = __builtin_amdgcn_mfma_f32_16x16x32_bf16(Hb, W1[1][1], dH1, 0, 0, 0);
            dH2 = __builtin_amdgcn_mfma_f32_16x16x32_bf16(Hb, W1[2][1], dH2, 0, 0, 0);
            dH3 = __builtin_amdgcn_mfma_f32_16x16x32_bf16(Hb, W1[3][1], dH3, 0, 0, 0);
            dG0 = __builtin_amdgcn_mfma_f32_16x16x32_bf16(Gb, W1[0][3], dG0, 0, 0, 0);
            dG1 = __builtin_amdgcn_mfma_f32_16x16x32_bf16(Gb, W1[1][3], dG1, 0, 0, 0);
            dG2 = __builtin_amdgcn_mfma_f32_16x16x32_bf16(Gb, W1[2][3], dG2, 0, 0, 0);
            dG3 = __builtin_amdgcn_mfma_f32_16x16x32_bf16(Gb, W1[3][3], dG3, 0, 0, 0);
            __builtin_amdgcn_s_setprio(0);
            float sa = half ? (dH1[0] + dG1[0]) : (dH0[0] + dG0[0]);
            float sb = half ? (dH3[0] + dG3[0]) : (dH2[0] + dG2[0]);
            float vA = __builtin_amdgcn_rcpf(1.0f + exp2_f(sa));
            float vB = fmaf(aselB, __builtin_amdgcn_rcpf(1.0f + exp2_f(sb)), cselB);
            float oA = __shfl_xor(vA, 32);
            float oB = __shfl_xor(vB, 32);
            float i_ = half ? oA : vA;
            float f_ = half ? vA : oA;
            float g_ = half ? oB : vB;
            float o_ = half ? vB : oB;
            c1s = fmaf(f_, c1s, i_ * g_);
            float tc = fmaf(2.0f, __builtin_amdgcn_rcpf(1.0f + exp2_f(c1s * (-2.0f * NLOG2E))), -1.0f);
            h1s = o_ * tc;
            if (lg < 2) {
                s_h1[P][lg][u] = f2bf(h1s);
                *opp = h1s;                  // out1[b,t]; stays in flight across BAR
            }
            opp += HID;
        };

        for (int it = 0; it < T_STEPS / 2 - 1; ++it) {
            l1_body(1); BAR();
            l1_body(0); BAR();
        }
        l1_body(1); BAR();
        l1_body(0);                          // last step, no barrier
        if (lg < 2) {
            out[BTH + BH + bi]     = h1s;   // h_n layer1
            out[BTH + 3 * BH + bi] = c1s;   // c_n layer1
        }
    }
    #undef BAR
}

extern "C" void kernel_launch(void* const* d_in, const int* in_sizes, int n_in,
                              void* d_out, int out_size, void* d_ws, size_t ws_size,
                              hipStream_t stream) {
    const float* x    = (const float*)d_in[0];
    const float* wih0 = (const float*)d_in[1];
    const float* whh0 = (const float*)d_in[2];
    const float* bih0 = (const float*)d_in[3];
    const float* bhh0 = (const float*)d_in[4];
    const float* wih1 = (const float*)d_in[5];
    const float* whh1 = (const float*)d_in[6];
    const float* bih1 = (const float*)d_in[7];
    const float* bhh1 = (const float*)d_in[8];
    float* out = (float*)d_out;

    const int B = in_sizes[0] / (T_STEPS * 4);   // 512

    lstm2_ts<<<dim3(B / 2), dim3(512), 0, stream>>>(
        x, wih0, whh0, bih0, bhh0, wih1, whh1, bih1, bhh1, out, B);
}

// Round 13
// 649.501 us; speedup vs baseline: 1.5295x; 1.2125x over previous
//
#include <hip/hip_runtime.h>

#define T_STEPS 2048
#define HID 64

typedef __attribute__((ext_vector_type(4))) int   int4v;
typedef __attribute__((ext_vector_type(4))) float f32x4;

static __device__ __forceinline__ float exp2_f(float x) {
#if __has_builtin(__builtin_amdgcn_exp2f)
    return __builtin_amdgcn_exp2f(x);
#else
    return exp2f(x);
#endif
}
#define NLOG2E 1.4426950408889634f

// R13 = R9 schedule + INT8 MFMA (K=64).
// Two batches/block (256 blocks, 1/CU), 8 waves: 0-3 = L0, 4-7 = L1, skewed
// one step, ONE raw s_barrier per step (lgkmcnt-only wait).
// mfma_i32_16x16x64_i8: L0 = 4 MFMAs/step (was 8 bf16), L1 = 8 (was 16) ->
// MFMA pipe 466 -> ~245 cy/step/SIMD.
// Quantization: h at fixed scale 127 (|h|<1, abs err <= 0.004); weights
// per-gate-row scale rowmax/127 (cross-lane max via 2 shfl_xor at setup);
// i32 accumulation exact; dequant scale folds the exp2 activation constant.
// x-path (K=4) stays exact f32 VALU; c-state f32; outputs store f32 h.
// A/B i8 frags use the same (lane,byte)->k map, so internal permutation
// cancels in the dot product (same consistency argument as bf16, R3-verified).
__global__ void __launch_bounds__(512, 1) __attribute__((amdgpu_waves_per_eu(2, 2)))
lstm2_i8(const float* __restrict__ x,
         const float* __restrict__ wih0, const float* __restrict__ whh0,
         const float* __restrict__ bih0, const float* __restrict__ bhh0,
         const float* __restrict__ wih1, const float* __restrict__ whh1,
         const float* __restrict__ bih1, const float* __restrict__ bhh1,
         float* __restrict__ out, int B)
{
    // h state as i8 [pingpong][batch][unit]; low LDS offsets
    __shared__ __align__(16) char s_h0q[2][2][HID];
    __shared__ __align__(16) char s_h1q[2][2][HID];
    __shared__ __align__(16) float s_xf[2 * T_STEPS * 4];    // 64 KB x f32

    const int tid  = threadIdx.x;
    const int lane = tid & 63;
    const int wv   = tid >> 6;       // wave 0..7
    const int wg   = wv >> 2;        // 0 = L0 group, 1 = L1 group
    const int wl   = wv & 3;         // units 16wl..16wl+15
    const int l15  = lane & 15;
    const int lg   = lane >> 4;      // k-block; lg0/1 = batch0/1 for acts
    const int b0   = 2 * blockIdx.x;
    const int u    = 16 * wl + l15;
    const int bx   = lg & 1;
    const int rsel = (l15 >> 2) & 1; // A rows 0,8 -> b0; 4,12 -> b1

    const float SCL[4] = {-NLOG2E, -NLOG2E, -2.0f * NLOG2E, -NLOG2E};

    // ---------------- stage x, zero h ----------------
    const float4* __restrict__ xb4 = (const float4*)(x + (size_t)b0 * (T_STEPS * 4));
    float4* s_xf4 = (float4*)s_xf;
    for (int i2 = tid; i2 < 2 * T_STEPS; i2 += 512) s_xf4[i2] = xb4[i2];
    if (tid < 256) {
        ((char*)s_h0q)[tid] = 0;
        ((char*)s_h1q)[tid] = 0;
    }

    const size_t BTH = (size_t)B * T_STEPS * HID;
    const size_t BH  = (size_t)B * HID;
    const size_t bi  = (size_t)(b0 + bx) * HID + u;
    const int4v Zi = {0, 0, 0, 0};

    // quantize one 16-element k-slice of a weight row (already gathered),
    // given qscale; pack to 16 bytes
    auto pack16 = [&](const float* wr, float qs) {
        int4v r;
        #pragma unroll
        for (int dw = 0; dw < 4; ++dw) {
            unsigned d = 0;
            #pragma unroll
            for (int bbb = 0; bbb < 4; ++bbb) {
                int q = (int)rintf(wr[dw * 4 + bbb] * qs);
                d |= ((unsigned)(q & 255)) << (8 * bbb);
            }
            r[dw] = (int)d;
        }
        return r;
    };
    // full-row absmax across k (16 local + cross-lg butterfly)
    auto rowmax = [&](const float* wr) {
        float mx = 0.f;
        #pragma unroll
        for (int j = 0; j < 16; ++j) mx = fmaxf(mx, fabsf(wr[j]));
        mx = fmaxf(mx, __shfl_xor(mx, 16));
        mx = fmaxf(mx, __shfl_xor(mx, 32));
        return fmaxf(mx, 1e-20f);
    };

    #define BAR() do { asm volatile("s_waitcnt lgkmcnt(0)" ::: "memory"); \
                       __builtin_amdgcn_s_barrier(); } while (0)

    if (wg == 0) {
        // =================== layer0 wave group ===================
        int4v W0q[4];        // Whh0 rows quantized (K=64, one frag each)
        float dq0[4];        // dequant * SCL
        float wx[4][4];      // Wih0 rows * SCL (f32 exact)
        float b0s[4];        // bias * SCL
        #pragma unroll
        for (int ni = 0; ni < 4; ++ni) {
            const int g = 64 * ni + u;
            float wr[16];
            #pragma unroll
            for (int j = 0; j < 16; ++j) wr[j] = whh0[g * HID + 16 * lg + j];
            float mx = rowmax(wr);
            W0q[ni] = pack16(wr, 127.f / mx);
            dq0[ni] = (mx / (127.f * 127.f)) * SCL[ni];
            #pragma unroll
            for (int j = 0; j < 4; ++j) wx[ni][j] = wih0[g * 4 + j] * SCL[ni];
            b0s[ni] = (bih0[g] + bhh0[g]) * SCL[ni];
        }
        float c0s = 0.f, h0s = 0.f;
        const float* xcur = &s_xf[(size_t)bx * T_STEPS * 4];
        __syncthreads();   // staging visible

        auto l0_body = [&](int P) {
            const int Q = P ^ 1;
            const int4v Ha = *(const int4v*)&s_h0q[Q][rsel][16 * lg];  // h0(t-1) i8
            const float4 xt = *(const float4*)xcur;  xcur += 4;
            __builtin_amdgcn_s_setprio(1);
            int4v a0 = __builtin_amdgcn_mfma_i32_16x16x64_i8(Ha, W0q[0], Zi, 0, 0, 0);
            int4v a1 = __builtin_amdgcn_mfma_i32_16x16x64_i8(Ha, W0q[1], Zi, 0, 0, 0);
            int4v a2 = __builtin_amdgcn_mfma_i32_16x16x64_i8(Ha, W0q[2], Zi, 0, 0, 0);
            int4v a3 = __builtin_amdgcn_mfma_i32_16x16x64_i8(Ha, W0q[3], Zi, 0, 0, 0);
            __builtin_amdgcn_s_setprio(0);
            // x-chain (independent of MFMA) carries the bias
            float t0 = fmaf(wx[0][0], xt.x, b0s[0]);
            float t1 = fmaf(wx[1][0], xt.x, b0s[1]);
            float t2 = fmaf(wx[2][0], xt.x, b0s[2]);
            float t3 = fmaf(wx[3][0], xt.x, b0s[3]);
            t0 = fmaf(wx[0][1], xt.y, t0); t0 = fmaf(wx[0][2], xt.z, t0); t0 = fmaf(wx[0][3], xt.w, t0);
            t1 = fmaf(wx[1][1], xt.y, t1); t1 = fmaf(wx[1][2], xt.z, t1); t1 = fmaf(wx[1][3], xt.w, t1);
            t2 = fmaf(wx[2][1], xt.y, t2); t2 = fmaf(wx[2][2], xt.z, t2); t2 = fmaf(wx[2][3], xt.w, t2);
            t3 = fmaf(wx[3][1], xt.y, t3); t3 = fmaf(wx[3][2], xt.z, t3); t3 = fmaf(wx[3][3], xt.w, t3);
            float s0 = fmaf((float)a0[0], dq0[0], t0);
            float s1 = fmaf((float)a1[0], dq0[1], t1);
            float s2 = fmaf((float)a2[0], dq0[2], t2);
            float s3 = fmaf((float)a3[0], dq0[3], t3);
            float i_ = __builtin_amdgcn_rcpf(1.0f + exp2_f(s0));
            float f_ = __builtin_amdgcn_rcpf(1.0f + exp2_f(s1));
            float g_ = fmaf(2.0f, __builtin_amdgcn_rcpf(1.0f + exp2_f(s2)), -1.0f);
            float o_ = __builtin_amdgcn_rcpf(1.0f + exp2_f(s3));
            c0s = fmaf(f_, c0s, i_ * g_);
            h0s = o_ * fmaf(2.0f, __builtin_amdgcn_rcpf(1.0f + exp2_f(c0s * (-2.0f * NLOG2E))), -1.0f);
            if (lg < 2) s_h0q[P][lg][u] = (char)(int)rintf(h0s * 127.f);
        };

        for (int it = 0; it < T_STEPS / 2; ++it) {
            l0_body(0); BAR();
            l0_body(1); BAR();
        }
        if (lg < 2) {
            out[BTH + bi]          = h0s;   // h_n layer0 (f32, pre-quant)
            out[BTH + 2 * BH + bi] = c0s;   // c_n layer0
        }
    } else {
        // =================== layer1 wave group ===================
        int4v Wihq[4], Whhq[4];
        float dqih[4], dqhh[4], b1s[4];
        #pragma unroll
        for (int ni = 0; ni < 4; ++ni) {
            const int g = 64 * ni + u;
            float wr[16];
            #pragma unroll
            for (int j = 0; j < 16; ++j) wr[j] = wih1[g * HID + 16 * lg + j];
            float mxi = rowmax(wr);
            Wihq[ni] = pack16(wr, 127.f / mxi);
            dqih[ni] = (mxi / (127.f * 127.f)) * SCL[ni];
            #pragma unroll
            for (int j = 0; j < 16; ++j) wr[j] = whh1[g * HID + 16 * lg + j];
            float mxh = rowmax(wr);
            Whhq[ni] = pack16(wr, 127.f / mxh);
            dqhh[ni] = (mxh / (127.f * 127.f)) * SCL[ni];
            b1s[ni] = (bih1[g] + bhh1[g]) * SCL[ni];
        }
        float c1s = 0.f, h1s = 0.f;
        float* __restrict__ opp = out + (size_t)(b0 + bx) * T_STEPS * HID + u;
        __syncthreads();   // staging visible
        BAR();             // matches L0's first barrier (L1 idle in window 0)

        auto l1_body = [&](int P) {
            const int Q = P ^ 1;
            const int4v Ha = *(const int4v*)&s_h0q[Q][rsel][16 * lg];  // h0(t)
            const int4v Ga = *(const int4v*)&s_h1q[Q][rsel][16 * lg];  // h1(t-1)
            __builtin_amdgcn_s_setprio(1);
            int4v dH0 = __builtin_amdgcn_mfma_i32_16x16x64_i8(Ha, Wihq[0], Zi, 0, 0, 0);
            int4v dH1 = __builtin_amdgcn_mfma_i32_16x16x64_i8(Ha, Wihq[1], Zi, 0, 0, 0);
            int4v dH2 = __builtin_amdgcn_mfma_i32_16x16x64_i8(Ha, Wihq[2], Zi, 0, 0, 0);
            int4v dH3 = __builtin_amdgcn_mfma_i32_16x16x64_i8(Ha, Wihq[3], Zi, 0, 0, 0);
            int4v dG0 = __builtin_amdgcn_mfma_i32_16x16x64_i8(Ga, Whhq[0], Zi, 0, 0, 0);
            int4v dG1 = __builtin_amdgcn_mfma_i32_16x16x64_i8(Ga, Whhq[1], Zi, 0, 0, 0);
            int4v dG2 = __builtin_amdgcn_mfma_i32_16x16x64_i8(Ga, Whhq[2], Zi, 0, 0, 0);
            int4v dG3 = __builtin_amdgcn_mfma_i32_16x16x64_i8(Ga, Whhq[3], Zi, 0, 0, 0);
            __builtin_amdgcn_s_setprio(0);
            float s0 = fmaf((float)dG0[0], dqhh[0], fmaf((float)dH0[0], dqih[0], b1s[0]));
            float s1 = fmaf((float)dG1[0], dqhh[1], fmaf((float)dH1[0], dqih[1], b1s[1]));
            float s2 = fmaf((float)dG2[0], dqhh[2], fmaf((float)dH2[0], dqih[2], b1s[2]));
            float s3 = fmaf((float)dG3[0], dqhh[3], fmaf((float)dH3[0], dqih[3], b1s[3]));
            float i_ = __builtin_amdgcn_rcpf(1.0f + exp2_f(s0));
            float f_ = __builtin_amdgcn_rcpf(1.0f + exp2_f(s1));
            float g_ = fmaf(2.0f, __builtin_amdgcn_rcpf(1.0f + exp2_f(s2)), -1.0f);
            float o_ = __builtin_amdgcn_rcpf(1.0f + exp2_f(s3));
            c1s = fmaf(f_, c1s, i_ * g_);
            h1s = o_ * fmaf(2.0f, __builtin_amdgcn_rcpf(1.0f + exp2_f(c1s * (-2.0f * NLOG2E))), -1.0f);
            if (lg < 2) {
                s_h1q[P][lg][u] = (char)(int)rintf(h1s * 127.f);
                *opp = h1s;                  // out1 (f32); stays in flight across BAR
            }
            opp += HID;
        };

        for (int it = 0; it < T_STEPS / 2 - 1; ++it) {
            l1_body(1); BAR();
            l1_body(0); BAR();
        }
        l1_body(1); BAR();
        l1_body(0);                          // last step, no barrier
        if (lg < 2) {
            out[BTH + BH + bi]     = h1s;   // h_n layer1
            out[BTH + 3 * BH + bi] = c1s;   // c_n layer1
        }
    }
    #undef BAR
}

extern "C" void kernel_launch(void* const* d_in, const int* in_sizes, int n_in,
                              void* d_out, int out_size, void* d_ws, size_t ws_size,
                              hipStream_t stream) {
    const float* x    = (const float*)d_in[0];
    const float* wih0 = (const float*)d_in[1];
    const float* whh0 = (const float*)d_in[2];
    const float* bih0 = (const float*)d_in[3];
    const float* bhh0 = (const float*)d_in[4];
    const float* wih1 = (const float*)d_in[5];
    const float* whh1 = (const float*)d_in[6];
    const float* bih1 = (const float*)d_in[7];
    const float* bhh1 = (const float*)d_in[8];
    float* out = (float*)d_out;

    const int B = in_sizes[0] / (T_STEPS * 4);   // 512

    lstm2_i8<<<dim3(B / 2), dim3(512), 0, stream>>>(
        x, wih0, whh0, bih0, bhh0, wih1, whh1, bih1, bhh1, out, B);
}